// Round 1
// baseline (434.434 us; speedup 1.0000x reference)
//
#include <hip/hip_runtime.h>
#include <hip/hip_bf16.h>
#include <math.h>

// B=2, SX=SY=2048, XD=YD=1024, P=64, H=16, MULT=4
typedef __bf16 bf16_t;
typedef __bf16 bf16x8 __attribute__((ext_vector_type(8)));
typedef __bf16 bf16x4 __attribute__((ext_vector_type(4)));
typedef float f32x4 __attribute__((ext_vector_type(4)));

static __device__ __forceinline__ f32x4 mfma16(bf16x8 a, bf16x8 b, f32x4 c) {
  return __builtin_amdgcn_mfma_f32_16x16x32_bf16(a, b, c, 0, 0, 0);
}

static __device__ __forceinline__ float gelu_f(float x) {
  return 0.5f * x * (1.0f + erff(x * 0.70710678118654752440f));
}

// ---------------- LayerNorm over D=1024, fp32 in -> bf16 out ----------------
__global__ __launch_bounds__(256) void ln_kernel(const float* __restrict__ in,
                                                 const float* __restrict__ g,
                                                 const float* __restrict__ be,
                                                 bf16_t* __restrict__ out) {
  const int row = blockIdx.x, t = threadIdx.x;
  const float4 xv = ((const float4*)(in + (long)row * 1024))[t];
  float s1 = xv.x + xv.y + xv.z + xv.w;
  float s2 = xv.x * xv.x + xv.y * xv.y + xv.z * xv.z + xv.w * xv.w;
#pragma unroll
  for (int m = 1; m < 64; m <<= 1) {
    s1 += __shfl_xor(s1, m);
    s2 += __shfl_xor(s2, m);
  }
  __shared__ float r1[4], r2[4];
  if ((t & 63) == 0) { r1[t >> 6] = s1; r2[t >> 6] = s2; }
  __syncthreads();
  s1 = r1[0] + r1[1] + r1[2] + r1[3];
  s2 = r2[0] + r2[1] + r2[2] + r2[3];
  const float mean = s1 * (1.0f / 1024.0f);
  float var = s2 * (1.0f / 1024.0f) - mean * mean;
  const float rstd = rsqrtf(fmaxf(var, 0.0f) + 1e-5f);
  const float4 gv = ((const float4*)g)[t];
  const float4 bv = ((const float4*)be)[t];
  bf16x4 o;
  o[0] = (bf16_t)((xv.x - mean) * rstd * gv.x + bv.x);
  o[1] = (bf16_t)((xv.y - mean) * rstd * gv.y + bv.y);
  o[2] = (bf16_t)((xv.z - mean) * rstd * gv.z + bv.z);
  o[3] = (bf16_t)((xv.w - mean) * rstd * gv.w + bv.w);
  *(bf16x4*)(out + (long)row * 1024 + t * 4) = o;
}

// ------------- tiled transpose+cast: out[b][j][i] = (bf16)in[b][i][j] -------------
template <typename TIN>
__global__ __launch_bounds__(256) void transpose_cast(const TIN* __restrict__ in,
                                                      bf16_t* __restrict__ out,
                                                      int istride, int ibatch,
                                                      int ostride, int obatch) {
  __shared__ bf16_t tile[64][65];
  const TIN* ip = in + (long)blockIdx.z * ibatch;
  bf16_t* op = out + (long)blockIdx.z * obatch;
  const int i0 = blockIdx.x * 64, j0 = blockIdx.y * 64;
  const int r = threadIdx.x >> 2, cs = (threadIdx.x & 3) * 16;
#pragma unroll
  for (int jj = 0; jj < 16; jj++)
    tile[cs + jj][r] = (bf16_t)(float)ip[(long)(i0 + r) * istride + j0 + cs + jj];
  __syncthreads();
#pragma unroll
  for (int jj = 0; jj < 16; jj++)
    op[(long)(j0 + r) * ostride + i0 + cs + jj] = tile[r][cs + jj];
}

// ---------------- GEMM: C[M,N] = A[M,K] @ Bt[N,K]^T, bf16 in, fp32 acc ----------------
// EPI: 0 = bias -> bf16 ; 1 = bias + res -> fp32 ; 2 = gelu(bias) -> bf16
template <int EPI>
__global__ __launch_bounds__(256) void gemm_bt(const bf16_t* __restrict__ A,
                                               const bf16_t* __restrict__ Bt,
                                               const float* __restrict__ bias,
                                               const float* __restrict__ res,
                                               void* __restrict__ Cout,
                                               int M, int N, int K) {
  __shared__ bf16_t a_lds[128 * 40];
  __shared__ bf16_t b_lds[128 * 40];
  const int tid = threadIdx.x;
  const int l = tid & 63, w = tid >> 6;
  const int wr = w >> 1, wc = w & 1;
  const int m0 = blockIdx.y * 128, n0 = blockIdx.x * 128;
  const int r0 = tid >> 2, c8 = (tid & 3) * 8;
  const int lr = l & 15, lk = (l >> 4) * 8;
  f32x4 acc[4][4] = {};
  for (int k0 = 0; k0 < K; k0 += 32) {
    __syncthreads();
    *(bf16x8*)&a_lds[r0 * 40 + c8] = *(const bf16x8*)&A[(long)(m0 + r0) * K + k0 + c8];
    *(bf16x8*)&a_lds[(r0 + 64) * 40 + c8] = *(const bf16x8*)&A[(long)(m0 + r0 + 64) * K + k0 + c8];
    *(bf16x8*)&b_lds[r0 * 40 + c8] = *(const bf16x8*)&Bt[(long)(n0 + r0) * K + k0 + c8];
    *(bf16x8*)&b_lds[(r0 + 64) * 40 + c8] = *(const bf16x8*)&Bt[(long)(n0 + r0 + 64) * K + k0 + c8];
    __syncthreads();
    bf16x8 af[4], bfr[4];
#pragma unroll
    for (int m = 0; m < 4; m++) af[m] = *(bf16x8*)&a_lds[(wr * 64 + m * 16 + lr) * 40 + lk];
#pragma unroll
    for (int n = 0; n < 4; n++) bfr[n] = *(bf16x8*)&b_lds[(wc * 64 + n * 16 + lr) * 40 + lk];
#pragma unroll
    for (int m = 0; m < 4; m++)
#pragma unroll
      for (int n = 0; n < 4; n++) acc[m][n] = mfma16(af[m], bfr[n], acc[m][n]);
  }
#pragma unroll
  for (int m = 0; m < 4; m++)
#pragma unroll
    for (int n = 0; n < 4; n++) {
      const int row_b = m0 + wr * 64 + m * 16 + (l >> 4) * 4;
      const int col = n0 + wc * 64 + n * 16 + lr;
      const float bia = bias[col];
#pragma unroll
      for (int r = 0; r < 4; r++) {
        const long idx = (long)(row_b + r) * N + col;
        const float v = acc[m][n][r] + bia;
        if (EPI == 0) ((bf16_t*)Cout)[idx] = (bf16_t)v;
        if (EPI == 1) ((float*)Cout)[idx] = v + res[idx];
        if (EPI == 2) ((bf16_t*)Cout)[idx] = (bf16_t)gelu_f(v);
      }
    }
}

// ---------------- fused attention ----------------
__global__ __launch_bounds__(256) void attn_kernel(const bf16_t* __restrict__ qg,
                                                   const bf16_t* __restrict__ kg,
                                                   const bf16_t* __restrict__ vtg,
                                                   bf16_t* __restrict__ og,
                                                   const int* __restrict__ maskp) {
  const int S = 2048, T = 2048, HP = 1024, P = 64;
  __shared__ bf16_t q_lds[64 * 80], k_lds[64 * 80], vt_lds[64 * 80], p_lds[64 * 80];
  const int bh = blockIdx.y, b = bh >> 4, h = bh & 15;
  const int q0 = blockIdx.x * 64;
  const bf16_t* qp = qg + (long)(b * S + q0) * HP + h * P;
  const bf16_t* kp = kg + (long)b * T * HP + h * P;
  const bf16_t* vp = vtg + (long)bh * P * T;
  const int tid = threadIdx.x, l = tid & 63, w = tid >> 6;
  const int lr = l & 15, lg = l >> 4;
  const bool do_mask = (maskp[0] != 0);
  const int sr = tid >> 2, sc = (tid & 3) * 8;
  *(bf16x8*)&q_lds[sr * 80 + sc] = *(const bf16x8*)&qp[sr * HP + sc];
  *(bf16x8*)&q_lds[sr * 80 + sc + 32] = *(const bf16x8*)&qp[sr * HP + sc + 32];

  float mrun[4], lrun[4];
  f32x4 oacc[4] = {};
#pragma unroll
  for (int r = 0; r < 4; r++) { mrun[r] = -1e30f; lrun[r] = 0.0f; }

  for (int t0 = 0; t0 < T; t0 += 64) {
    __syncthreads();
    *(bf16x8*)&k_lds[sr * 80 + sc] = *(const bf16x8*)&kp[(long)(t0 + sr) * HP + sc];
    *(bf16x8*)&k_lds[sr * 80 + sc + 32] = *(const bf16x8*)&kp[(long)(t0 + sr) * HP + sc + 32];
    *(bf16x8*)&vt_lds[sr * 80 + sc] = *(const bf16x8*)&vp[(long)sr * T + t0 + sc];
    *(bf16x8*)&vt_lds[sr * 80 + sc + 32] = *(const bf16x8*)&vp[(long)sr * T + t0 + sc + 32];
    __syncthreads();
    f32x4 sacc[4] = {};
    bf16x8 aq0 = *(bf16x8*)&q_lds[(w * 16 + lr) * 80 + lg * 8];
    bf16x8 aq1 = *(bf16x8*)&q_lds[(w * 16 + lr) * 80 + 32 + lg * 8];
#pragma unroll
    for (int n = 0; n < 4; n++) {
      bf16x8 bk0 = *(bf16x8*)&k_lds[(n * 16 + lr) * 80 + lg * 8];
      bf16x8 bk1 = *(bf16x8*)&k_lds[(n * 16 + lr) * 80 + 32 + lg * 8];
      sacc[n] = mfma16(aq0, bk0, sacc[n]);
      sacc[n] = mfma16(aq1, bk1, sacc[n]);
    }
#pragma unroll
    for (int r = 0; r < 4; r++) {
      float sv[4];
      float tmax = -1e30f;
#pragma unroll
      for (int n = 0; n < 4; n++) {
        sv[n] = sacc[n][r] * 0.125f;
        tmax = fmaxf(tmax, sv[n]);
      }
#pragma unroll
      for (int mm = 1; mm < 16; mm <<= 1) tmax = fmaxf(tmax, __shfl_xor(tmax, mm));
      const float mnew = fmaxf(mrun[r], tmax);
      const float f = __expf(mrun[r] - mnew);
      float pvv[4], psum = 0.0f;
#pragma unroll
      for (int n = 0; n < 4; n++) {
        pvv[n] = __expf(sv[n] - mnew);
        psum += pvv[n];
      }
#pragma unroll
      for (int mm = 1; mm < 16; mm <<= 1) psum += __shfl_xor(psum, mm);
      lrun[r] = lrun[r] * f + psum;
      mrun[r] = mnew;
#pragma unroll
      for (int n = 0; n < 4; n++) oacc[n][r] *= f;
      const int srow_loc = w * 16 + lg * 4 + r;
      const int sglob = q0 + srow_loc;
#pragma unroll
      for (int n = 0; n < 4; n++) {
        const int tloc = n * 16 + lr;
        float pw = pvv[n];
        if (do_mask && (t0 + tloc) <= sglob) pw = 0.0f;
        p_lds[srow_loc * 80 + tloc] = (bf16_t)pw;
      }
    }
    __syncthreads();
#pragma unroll
    for (int kk = 0; kk < 2; kk++) {
      bf16x8 pa = *(bf16x8*)&p_lds[(w * 16 + lr) * 80 + kk * 32 + lg * 8];
#pragma unroll
      for (int n = 0; n < 4; n++) {
        bf16x8 vbf = *(bf16x8*)&vt_lds[(n * 16 + lr) * 80 + kk * 32 + lg * 8];
        oacc[n] = mfma16(pa, vbf, oacc[n]);
      }
    }
  }
#pragma unroll
  for (int n = 0; n < 4; n++)
#pragma unroll
    for (int r = 0; r < 4; r++) {
      const int srow = q0 + w * 16 + lg * 4 + r;
      const int col = h * P + n * 16 + lr;
      og[(long)(b * S + srow) * HP + col] = (bf16_t)(oacc[n][r] / lrun[r]);
    }
}

extern "C" void kernel_launch(void* const* d_in, const int* in_sizes, int n_in,
                              void* d_out, int out_size, void* d_ws, size_t ws_size,
                              hipStream_t stream) {
  const float* x = (const float*)d_in[0];
  const float* y = (const float*)d_in[1];
  const float* gxg = (const float*)d_in[2];
  const float* gxb = (const float*)d_in[3];
  const float* gyg = (const float*)d_in[4];
  const float* gyb = (const float*)d_in[5];
  const float* Wq = (const float*)d_in[6];
  const float* bq = (const float*)d_in[7];
  const float* Wk = (const float*)d_in[8];
  const float* bk = (const float*)d_in[9];
  const float* Wv = (const float*)d_in[10];
  const float* bv = (const float*)d_in[11];
  const float* Wo = (const float*)d_in[12];
  const float* bo = (const float*)d_in[13];
  const float* gdg = (const float*)d_in[14];
  const float* gdb = (const float*)d_in[15];
  const float* W1 = (const float*)d_in[16];
  const float* b1 = (const float*)d_in[17];
  const float* W2 = (const float*)d_in[18];
  const float* b2 = (const float*)d_in[19];
  const int* maskp = (const int*)d_in[20];
  float* out = (float*)d_out;

  char* ws = (char*)d_ws;
  const long MB = 1024 * 1024;
  bf16_t* xn = (bf16_t*)(ws + 0);
  bf16_t* yn = (bf16_t*)(ws + 8 * MB);
  bf16_t* WqT = (bf16_t*)(ws + 16 * MB);
  bf16_t* WkT = (bf16_t*)(ws + 18 * MB);
  bf16_t* WvT = (bf16_t*)(ws + 20 * MB);
  bf16_t* WoT = (bf16_t*)(ws + 22 * MB);
  bf16_t* W1T = (bf16_t*)(ws + 24 * MB);
  bf16_t* W2T = (bf16_t*)(ws + 32 * MB);
  bf16_t* qb = (bf16_t*)(ws + 40 * MB);
  bf16_t* kb = (bf16_t*)(ws + 48 * MB);
  bf16_t* vb = (bf16_t*)(ws + 56 * MB);
  bf16_t* vTb = (bf16_t*)(ws + 64 * MB);
  bf16_t* ob = (bf16_t*)(ws + 0);
  bf16_t* xd = (bf16_t*)(ws + 8 * MB);
  bf16_t* hb = (bf16_t*)(ws + 40 * MB);

  transpose_cast<float><<<dim3(16, 1, 16), 256, 0, stream>>>(Wq, WqT, 64, 65536, 1024, 65536);
  transpose_cast<float><<<dim3(16, 1, 16), 256, 0, stream>>>(Wk, WkT, 64, 65536, 1024, 65536);
  transpose_cast<float><<<dim3(16, 1, 16), 256, 0, stream>>>(Wv, WvT, 64, 65536, 1024, 65536);
  transpose_cast<float><<<dim3(16, 16, 1), 256, 0, stream>>>(Wo, WoT, 1024, 0, 1024, 0);
  transpose_cast<float><<<dim3(16, 64, 1), 256, 0, stream>>>(W1, W1T, 4096, 0, 1024, 0);
  transpose_cast<float><<<dim3(64, 16, 1), 256, 0, stream>>>(W2, W2T, 1024, 0, 4096, 0);
  ln_kernel<<<4096, 256, 0, stream>>>(x, gxg, gxb, xn);
  ln_kernel<<<4096, 256, 0, stream>>>(y, gyg, gyb, yn);
  gemm_bt<0><<<dim3(8, 32), 256, 0, stream>>>(xn, WqT, bq, nullptr, qb, 4096, 1024, 1024);
  gemm_bt<0><<<dim3(8, 32), 256, 0, stream>>>(yn, WkT, bk, nullptr, kb, 4096, 1024, 1024);
  gemm_bt<0><<<dim3(8, 32), 256, 0, stream>>>(yn, WvT, bv, nullptr, vb, 4096, 1024, 1024);
  transpose_cast<__bf16><<<dim3(32, 1, 16), 256, 0, stream>>>(vb, vTb, 1024, 64, 2048, 131072);
  transpose_cast<__bf16><<<dim3(32, 1, 16), 256, 0, stream>>>(vb + (long)2048 * 1024, vTb + (long)16 * 131072, 1024, 64, 2048, 131072);
  attn_kernel<<<dim3(32, 32), 256, 0, stream>>>(qb, kb, vTb, ob, maskp);
  gemm_bt<1><<<dim3(8, 32), 256, 0, stream>>>(ob, WoT, bo, x, out, 4096, 1024, 1024);
  ln_kernel<<<4096, 256, 0, stream>>>(out, gdg, gdb, xd);
  gemm_bt<2><<<dim3(32, 32), 256, 0, stream>>>(xd, W1T, b1, nullptr, hb, 4096, 4096, 1024);
  gemm_bt<1><<<dim3(8, 32), 256, 0, stream>>>(hb, W2T, b2, out, out, 4096, 1024, 4096);
}

// Round 2
// 401.608 us; speedup vs baseline: 1.0817x; 1.0817x over previous
//
#include <hip/hip_runtime.h>
#include <hip/hip_bf16.h>
#include <math.h>

// B=2, SX=SY=2048, XD=YD=1024, P=64, H=16, MULT=4
typedef __bf16 bf16_t;
typedef __bf16 bf16x8 __attribute__((ext_vector_type(8)));
typedef __bf16 bf16x4 __attribute__((ext_vector_type(4)));
typedef float f32x4 __attribute__((ext_vector_type(4)));

#define QSCALE 0.18033688011112042f  /* 0.125 * log2(e): scores computed in log2 units */

static __device__ __forceinline__ f32x4 mfma16(bf16x8 a, bf16x8 b, f32x4 c) {
  return __builtin_amdgcn_mfma_f32_16x16x32_bf16(a, b, c, 0, 0, 0);
}

static __device__ __forceinline__ float gelu_f(float x) {
  return 0.5f * x * (1.0f + erff(x * 0.70710678118654752440f));
}

typedef __attribute__((address_space(1))) const void as1_void;
typedef __attribute__((address_space(3))) void as3_void;
static __device__ __forceinline__ void gload16(const void* g, void* s) {
  __builtin_amdgcn_global_load_lds((as1_void*)g, (as3_void*)s, 16, 0, 0);
}

// ---------------- LayerNorm over D=1024, fp32 in -> bf16 out ----------------
__global__ __launch_bounds__(256) void ln_kernel(const float* __restrict__ in,
                                                 const float* __restrict__ g,
                                                 const float* __restrict__ be,
                                                 bf16_t* __restrict__ out) {
  const int row = blockIdx.x, t = threadIdx.x;
  const float4 xv = ((const float4*)(in + (long)row * 1024))[t];
  float s1 = xv.x + xv.y + xv.z + xv.w;
  float s2 = xv.x * xv.x + xv.y * xv.y + xv.z * xv.z + xv.w * xv.w;
#pragma unroll
  for (int m = 1; m < 64; m <<= 1) {
    s1 += __shfl_xor(s1, m);
    s2 += __shfl_xor(s2, m);
  }
  __shared__ float r1[4], r2[4];
  if ((t & 63) == 0) { r1[t >> 6] = s1; r2[t >> 6] = s2; }
  __syncthreads();
  s1 = r1[0] + r1[1] + r1[2] + r1[3];
  s2 = r2[0] + r2[1] + r2[2] + r2[3];
  const float mean = s1 * (1.0f / 1024.0f);
  float var = s2 * (1.0f / 1024.0f) - mean * mean;
  const float rstd = rsqrtf(fmaxf(var, 0.0f) + 1e-5f);
  const float4 gv = ((const float4*)g)[t];
  const float4 bv = ((const float4*)be)[t];
  bf16x4 o;
  o[0] = (bf16_t)((xv.x - mean) * rstd * gv.x + bv.x);
  o[1] = (bf16_t)((xv.y - mean) * rstd * gv.y + bv.y);
  o[2] = (bf16_t)((xv.z - mean) * rstd * gv.z + bv.z);
  o[3] = (bf16_t)((xv.w - mean) * rstd * gv.w + bv.w);
  *(bf16x4*)(out + (long)row * 1024 + t * 4) = o;
}

// ------------- tiled transpose+cast: out[b][j][i] = (bf16)in[b][i][j] -------------
template <typename TIN>
__global__ __launch_bounds__(256) void transpose_cast(const TIN* __restrict__ in,
                                                      bf16_t* __restrict__ out,
                                                      int istride, int ibatch,
                                                      int ostride, int obatch) {
  __shared__ bf16_t tile[64][65];
  const TIN* ip = in + (long)blockIdx.z * ibatch;
  bf16_t* op = out + (long)blockIdx.z * obatch;
  const int i0 = blockIdx.x * 64, j0 = blockIdx.y * 64;
  const int r = threadIdx.x >> 2, cs = (threadIdx.x & 3) * 16;
#pragma unroll
  for (int jj = 0; jj < 16; jj++)
    tile[cs + jj][r] = (bf16_t)(float)ip[(long)(i0 + r) * istride + j0 + cs + jj];
  __syncthreads();
#pragma unroll
  for (int jj = 0; jj < 16; jj++)
    op[(long)(j0 + r) * ostride + i0 + cs + jj] = tile[r][cs + jj];
}

// ---------------- GEMM: C[M,N] = A[M,K] @ Bt[N,K]^T, bf16 in, fp32 acc ----------------
// m97 structure: linear LDS + global_load_lds width-16 staging, 2-barrier loop.
// EPI: 0 = bias -> bf16 ; 1 = bias + res -> fp32 ; 2 = gelu(bias) -> bf16 ;
//      3 = (bias) * QSCALE -> bf16 (Q projection, scale folded for attn log2 softmax)
template <int EPI>
__global__ __launch_bounds__(256) void gemm_bt(const bf16_t* __restrict__ A,
                                               const bf16_t* __restrict__ Bt,
                                               const float* __restrict__ bias,
                                               const float* __restrict__ res,
                                               void* __restrict__ Cout,
                                               int M, int N, int K) {
  __shared__ bf16_t a_lds[128 * 32];
  __shared__ bf16_t b_lds[128 * 32];
  const int tid = threadIdx.x;
  const int l = tid & 63, w = tid >> 6;
  const int wr = w >> 1, wc = w & 1;
  const int m0 = blockIdx.y * 128, n0 = blockIdx.x * 128;
  const int lr = l & 15, lk = (l >> 4) * 8;
  // staging geometry: wave w / inst i covers rows [i*64 + w*16, +16), lane l -> row + (l>>2), col (l&3)*8
  const int srow = w * 16 + (l >> 2), scol = (l & 3) * 8;
  const bf16_t* ag0 = A + (long)(m0 + srow) * K + scol;
  const bf16_t* ag1 = A + (long)(m0 + 64 + srow) * K + scol;
  const bf16_t* bg0 = Bt + (long)(n0 + srow) * K + scol;
  const bf16_t* bg1 = Bt + (long)(n0 + 64 + srow) * K + scol;
  bf16_t* al0 = &a_lds[w * 512];
  bf16_t* al1 = &a_lds[2048 + w * 512];
  bf16_t* bl0 = &b_lds[w * 512];
  bf16_t* bl1 = &b_lds[2048 + w * 512];
  f32x4 acc[4][4] = {};
  for (int k0 = 0; k0 < K; k0 += 32) {
    __syncthreads();
    gload16(ag0 + k0, al0);
    gload16(ag1 + k0, al1);
    gload16(bg0 + k0, bl0);
    gload16(bg1 + k0, bl1);
    __syncthreads();  // vmcnt(0) drained by compiler before barrier
    bf16x8 af[4], bfr[4];
#pragma unroll
    for (int m = 0; m < 4; m++) af[m] = *(bf16x8*)&a_lds[(wr * 64 + m * 16 + lr) * 32 + lk];
#pragma unroll
    for (int n = 0; n < 4; n++) bfr[n] = *(bf16x8*)&b_lds[(wc * 64 + n * 16 + lr) * 32 + lk];
#pragma unroll
    for (int m = 0; m < 4; m++)
#pragma unroll
      for (int n = 0; n < 4; n++) acc[m][n] = mfma16(af[m], bfr[n], acc[m][n]);
  }
#pragma unroll
  for (int m = 0; m < 4; m++)
#pragma unroll
    for (int n = 0; n < 4; n++) {
      const int row_b = m0 + wr * 64 + m * 16 + (l >> 4) * 4;
      const int col = n0 + wc * 64 + n * 16 + lr;
      const float bia = bias[col];
#pragma unroll
      for (int r = 0; r < 4; r++) {
        const long idx = (long)(row_b + r) * N + col;
        const float v = acc[m][n][r] + bia;
        if (EPI == 0) ((bf16_t*)Cout)[idx] = (bf16_t)v;
        if (EPI == 1) ((float*)Cout)[idx] = v + res[idx];
        if (EPI == 2) ((bf16_t*)Cout)[idx] = (bf16_t)gelu_f(v);
        if (EPI == 3) ((bf16_t*)Cout)[idx] = (bf16_t)(v * QSCALE);
      }
    }
}

// ---------------- fused attention (swapped-operand, in-lane softmax) ----------------
// QK^T computed as mfma(K,Q) -> D[t][s]: lane owns one s-row (s = lane&15) of scores.
// PV computed as mfma(V^T,P) -> O^T[p][s]: rescale stats stay lane-local.
// Q arrives pre-scaled by 0.125*log2e; softmax runs in exp2 domain.
// Denominator sums ALL t; mask (strict upper triu, post-softmax) only zeroes P.
__global__ __launch_bounds__(256) void attn_kernel(const bf16_t* __restrict__ qg,
                                                   const bf16_t* __restrict__ kg,
                                                   const bf16_t* __restrict__ vtg,
                                                   bf16_t* __restrict__ og,
                                                   const int* __restrict__ maskp) {
  const int S = 2048, T = 2048, HP = 1024;
  __shared__ bf16_t q_lds[64 * 72], k_lds[64 * 72], vt_lds[64 * 72], p_lds[64 * 72];
  const int bh = blockIdx.y, b = bh >> 4, h = bh & 15;
  const int q0 = blockIdx.x * 64;
  const bf16_t* qp = qg + (long)(b * S + q0) * HP + h * 64;
  const bf16_t* kp = kg + (long)b * T * HP + h * 64;
  const bf16_t* vp = vtg + (long)bh * 64 * T;
  const int tid = threadIdx.x, l = tid & 63, w = tid >> 6;
  const int lr = l & 15, lg = l >> 4, lg4 = lg * 4;
  const bool do_mask = (maskp[0] != 0);
  const int sr = tid >> 2, sc = (tid & 3) * 16;
  // stage Q once (rows sr, 32B chunks)
  *(bf16x8*)&q_lds[sr * 72 + sc] = *(const bf16x8*)&qp[(long)sr * HP + sc];
  *(bf16x8*)&q_lds[sr * 72 + sc + 8] = *(const bf16x8*)&qp[(long)sr * HP + sc + 8];
  // hoisted Q B-fragments (wave reads only its own 16 rows -> same-wave dep, no barrier)
  bf16x8 qf0 = *(bf16x8*)&q_lds[(w * 16 + lr) * 72 + lg * 8];
  bf16x8 qf1 = *(bf16x8*)&q_lds[(w * 16 + lr) * 72 + 32 + lg * 8];
  const int sglob = q0 + w * 16 + lr;  // the s-row this lane owns
  float mrun = -1e30f, lrun = 0.0f;
  f32x4 oat[4] = {};  // O^T: p = np*16 + lg4 + r, s = lr

  for (int t0 = 0; t0 < T; t0 += 64) {
    __syncthreads();  // prior tile's K/V frag reads complete
    *(bf16x8*)&k_lds[sr * 72 + sc] = *(const bf16x8*)&kp[(long)(t0 + sr) * HP + sc];
    *(bf16x8*)&k_lds[sr * 72 + sc + 8] = *(const bf16x8*)&kp[(long)(t0 + sr) * HP + sc + 8];
    *(bf16x8*)&vt_lds[sr * 72 + sc] = *(const bf16x8*)&vp[(long)sr * T + t0 + sc];
    *(bf16x8*)&vt_lds[sr * 72 + sc + 8] = *(const bf16x8*)&vp[(long)sr * T + t0 + sc + 8];
    __syncthreads();
    // S^T[t][s]: lane: s = lr, t = n*16 + lg4 + r (already log2-scaled via Q)
    f32x4 sacc[4] = {};
#pragma unroll
    for (int n = 0; n < 4; n++) {
      bf16x8 kf0 = *(bf16x8*)&k_lds[(n * 16 + lr) * 72 + lg * 8];
      bf16x8 kf1 = *(bf16x8*)&k_lds[(n * 16 + lr) * 72 + 32 + lg * 8];
      sacc[n] = mfma16(kf0, qf0, sacc[n]);
      sacc[n] = mfma16(kf1, qf1, sacc[n]);
    }
    // row max: 15 local fmax + 2 shuffles (lanes lr,lr+16,lr+32,lr+48 share row s=lr)
    float tm = sacc[0][0];
#pragma unroll
    for (int n = 0; n < 4; n++)
#pragma unroll
      for (int r = 0; r < 4; r++) tm = fmaxf(tm, sacc[n][r]);
    tm = fmaxf(tm, __shfl_xor(tm, 16));
    tm = fmaxf(tm, __shfl_xor(tm, 32));
    // defer-max (T13): only rescale when some row grew by > 8 (2^8 headroom in bf16 P)
    if (!__all(tm - mrun <= 8.0f)) {
      const float mnew = fmaxf(mrun, tm);
      const float f = exp2f(mrun - mnew);
      lrun *= f;
#pragma unroll
      for (int np = 0; np < 4; np++) oat[np] *= f;
      mrun = mnew;
    }
    float ps = 0.0f;
    float pv[4][4];
#pragma unroll
    for (int n = 0; n < 4; n++)
#pragma unroll
      for (int r = 0; r < 4; r++) {
        pv[n][r] = exp2f(sacc[n][r] - mrun);
        ps += pv[n][r];
      }
    ps += __shfl_xor(ps, 16);
    ps += __shfl_xor(ps, 32);
    lrun += ps;  // denominator over ALL t (mask is post-softmax)
    // mask + pack P -> per-wave-private p_lds rows [w*16, +16): 4x ds_write_b64
#pragma unroll
    for (int n = 0; n < 4; n++) {
      bf16x4 pk;
#pragma unroll
      for (int r = 0; r < 4; r++) {
        float v = pv[n][r];
        if (do_mask && (t0 + n * 16 + lg4 + r) <= sglob) v = 0.0f;
        pk[r] = (bf16_t)v;
      }
      *(bf16x4*)&p_lds[(w * 16 + lr) * 72 + n * 16 + lg4] = pk;
    }
    // O^T += V^T · P  (A = V^T rows p, B = P rows s; lane provides B row s = lr)
#pragma unroll
    for (int kk = 0; kk < 2; kk++) {
      bf16x8 pb = *(bf16x8*)&p_lds[(w * 16 + lr) * 72 + kk * 32 + lg * 8];
#pragma unroll
      for (int np = 0; np < 4; np++) {
        bf16x8 vtf = *(bf16x8*)&vt_lds[(np * 16 + lr) * 72 + kk * 32 + lg * 8];
        oat[np] = mfma16(vtf, pb, oat[np]);
      }
    }
  }
  // epilogue: normalize (stats lane-local!), transpose O^T -> O via p_lds, store
  const float inv = 1.0f / lrun;
#pragma unroll
  for (int np = 0; np < 4; np++) {
    bf16x4 o4;
#pragma unroll
    for (int r = 0; r < 4; r++) o4[r] = (bf16_t)(oat[np][r] * inv);
    *(bf16x4*)&p_lds[(w * 16 + lr) * 72 + np * 16 + lg4] = o4;
  }
  const int es = l >> 2, ec = (l & 3) * 16;
  bf16x8 o0 = *(bf16x8*)&p_lds[(w * 16 + es) * 72 + ec];
  bf16x8 o1 = *(bf16x8*)&p_lds[(w * 16 + es) * 72 + ec + 8];
  bf16_t* orow = og + (long)(b * S + q0 + w * 16 + es) * HP + h * 64 + ec;
  *(bf16x8*)&orow[0] = o0;
  *(bf16x8*)&orow[8] = o1;
}

extern "C" void kernel_launch(void* const* d_in, const int* in_sizes, int n_in,
                              void* d_out, int out_size, void* d_ws, size_t ws_size,
                              hipStream_t stream) {
  const float* x = (const float*)d_in[0];
  const float* y = (const float*)d_in[1];
  const float* gxg = (const float*)d_in[2];
  const float* gxb = (const float*)d_in[3];
  const float* gyg = (const float*)d_in[4];
  const float* gyb = (const float*)d_in[5];
  const float* Wq = (const float*)d_in[6];
  const float* bq = (const float*)d_in[7];
  const float* Wk = (const float*)d_in[8];
  const float* bk = (const float*)d_in[9];
  const float* Wv = (const float*)d_in[10];
  const float* bv = (const float*)d_in[11];
  const float* Wo = (const float*)d_in[12];
  const float* bo = (const float*)d_in[13];
  const float* gdg = (const float*)d_in[14];
  const float* gdb = (const float*)d_in[15];
  const float* W1 = (const float*)d_in[16];
  const float* b1 = (const float*)d_in[17];
  const float* W2 = (const float*)d_in[18];
  const float* b2 = (const float*)d_in[19];
  const int* maskp = (const int*)d_in[20];
  float* out = (float*)d_out;

  char* ws = (char*)d_ws;
  const long MB = 1024 * 1024;
  bf16_t* xn = (bf16_t*)(ws + 0);
  bf16_t* yn = (bf16_t*)(ws + 8 * MB);
  bf16_t* WqT = (bf16_t*)(ws + 16 * MB);
  bf16_t* WkT = (bf16_t*)(ws + 18 * MB);
  bf16_t* WvT = (bf16_t*)(ws + 20 * MB);
  bf16_t* WoT = (bf16_t*)(ws + 22 * MB);
  bf16_t* W1T = (bf16_t*)(ws + 24 * MB);
  bf16_t* W2T = (bf16_t*)(ws + 32 * MB);
  bf16_t* qb = (bf16_t*)(ws + 40 * MB);
  bf16_t* kb = (bf16_t*)(ws + 48 * MB);
  bf16_t* vb = (bf16_t*)(ws + 56 * MB);
  bf16_t* vTb = (bf16_t*)(ws + 64 * MB);
  bf16_t* ob = (bf16_t*)(ws + 0);
  bf16_t* xd = (bf16_t*)(ws + 8 * MB);
  bf16_t* hb = (bf16_t*)(ws + 40 * MB);

  transpose_cast<float><<<dim3(16, 1, 16), 256, 0, stream>>>(Wq, WqT, 64, 65536, 1024, 65536);
  transpose_cast<float><<<dim3(16, 1, 16), 256, 0, stream>>>(Wk, WkT, 64, 65536, 1024, 65536);
  transpose_cast<float><<<dim3(16, 1, 16), 256, 0, stream>>>(Wv, WvT, 64, 65536, 1024, 65536);
  transpose_cast<float><<<dim3(16, 16, 1), 256, 0, stream>>>(Wo, WoT, 1024, 0, 1024, 0);
  transpose_cast<float><<<dim3(16, 64, 1), 256, 0, stream>>>(W1, W1T, 4096, 0, 1024, 0);
  transpose_cast<float><<<dim3(64, 16, 1), 256, 0, stream>>>(W2, W2T, 1024, 0, 4096, 0);
  ln_kernel<<<4096, 256, 0, stream>>>(x, gxg, gxb, xn);
  ln_kernel<<<4096, 256, 0, stream>>>(y, gyg, gyb, yn);
  gemm_bt<3><<<dim3(8, 32), 256, 0, stream>>>(xn, WqT, bq, nullptr, qb, 4096, 1024, 1024);
  gemm_bt<0><<<dim3(8, 32), 256, 0, stream>>>(yn, WkT, bk, nullptr, kb, 4096, 1024, 1024);
  gemm_bt<0><<<dim3(8, 32), 256, 0, stream>>>(yn, WvT, bv, nullptr, vb, 4096, 1024, 1024);
  transpose_cast<__bf16><<<dim3(32, 1, 16), 256, 0, stream>>>(vb, vTb, 1024, 64, 2048, 131072);
  transpose_cast<__bf16><<<dim3(32, 1, 16), 256, 0, stream>>>(vb + (long)2048 * 1024, vTb + (long)16 * 131072, 1024, 64, 2048, 131072);
  attn_kernel<<<dim3(32, 32), 256, 0, stream>>>(qb, kb, vTb, ob, maskp);
  gemm_bt<1><<<dim3(8, 32), 256, 0, stream>>>(ob, WoT, bo, x, out, 4096, 1024, 1024);
  ln_kernel<<<4096, 256, 0, stream>>>(out, gdg, gdb, xd);
  gemm_bt<2><<<dim3(32, 32), 256, 0, stream>>>(xd, W1T, b1, nullptr, hb, 4096, 4096, 1024);
  gemm_bt<1><<<dim3(8, 32), 256, 0, stream>>>(hb, W2T, b2, out, out, 4096, 1024, 4096);
}